// Round 10
// baseline (458.843 us; speedup 1.0000x reference)
//
#include <hip/hip_runtime.h>
#include <math.h>

#define HEADS 3
#define CDIM 64
#define FDIM 256
#define HC 192      // HEADS*CDIM
#define HIDDIM 128
#define NEG 0.2f

#define SCAN_BLK 256
#define SCAN_ELEMS 1024  // 4 per thread; consumers use >>10

#define ASTR2 40   // LDS stride for A tiles (32 data + 8 pad shorts)
#define BSTR 264   // LDS stride for B^T tiles in gemm_attn (256 K + 8 pad)
#define BSTRB 200  // LDS stride for B^T tiles in gemm_beta (192 K + 8 pad)

typedef __attribute__((ext_vector_type(8))) short short8;
typedef __attribute__((ext_vector_type(4))) float f32x4;

__device__ __forceinline__ void atomicMaxF(float* addr, float val) {
    if (val >= 0.f) atomicMax((int*)addr, __float_as_int(val));
    else            atomicMin((unsigned int*)addr, __float_as_uint(val));
}

__device__ __forceinline__ unsigned short f2bf(float f) {
    unsigned int u = __float_as_uint(f);
    u = (u + 0x7FFFu + ((u >> 16) & 1u)) >> 16;   // RNE
    return (unsigned short)u;
}
__device__ __forceinline__ float bf2f(unsigned short u) {
    return __uint_as_float((unsigned int)u << 16);
}
__device__ __forceinline__ float leaky(float s) { return s >= 0.f ? s : NEG * s; }

// bijective chunked XCD swizzle (m204)
__device__ __forceinline__ int xcd_swizzle(int orig, int nwg) {
    int q = nwg >> 3, r = nwg & 7;
    int xcd = orig & 7, idx = orig >> 3;
    return (xcd < r ? xcd * (q + 1) : r * (q + 1) + (xcd - r) * q) + idx;
}

// ---------------- setup: weight transposes (y=0..3) + workspace zeroing (y=4) ----------------
__global__ __launch_bounds__(256) void setup(const float* __restrict__ wg_st,
                                             const float* __restrict__ wg_sc,
                                             const float* __restrict__ w1_st,
                                             const float* __restrict__ w1_sc,
                                             unsigned short* __restrict__ o0,
                                             unsigned short* __restrict__ o1,
                                             unsigned short* __restrict__ o2,
                                             unsigned short* __restrict__ o3,
                                             int* __restrict__ zero_base, int zero_ints) {
    int which = blockIdx.y;
    if (which == 4) {
        for (int i = blockIdx.x * 256 + threadIdx.x; i < zero_ints; i += gridDim.x * 256)
            zero_base[i] = 0;
        return;
    }
    const float* src = which == 0 ? wg_st : which == 1 ? wg_sc : which == 2 ? w1_st : w1_sc;
    unsigned short* dst = which == 0 ? o0 : which == 1 ? o1 : which == 2 ? o2 : o3;
    int K  = which < 2 ? FDIM : HC;
    int Nn = which < 2 ? HC : HIDDIM;
    int total = K * Nn;
    for (int idx = blockIdx.x * 256 + threadIdx.x; idx < total; idx += gridDim.x * 256) {
        int n = idx / K, k = idx - n * K;
        dst[idx] = f2bf(src[(size_t)k * Nn + n]);
    }
}

// ---------------- GEMM1 + attention-score epilogue (flattened, XCD-swizzled) ----------------
__global__ __launch_bounds__(256) void gemm_attn(const float* __restrict__ x_st,
                                                 const float* __restrict__ x_sc,
                                                 const unsigned short* __restrict__ wgT_st,
                                                 const unsigned short* __restrict__ wgT_sc,
                                                 const float* __restrict__ as_st,
                                                 const float* __restrict__ ad_st,
                                                 const float* __restrict__ as_sc,
                                                 const float* __restrict__ ad_sc,
                                                 unsigned short* __restrict__ h_bf,
                                                 float* __restrict__ ssrc,
                                                 float* __restrict__ sdst,
                                                 int M, int nrow) {
    __shared__ unsigned short As[128 * ASTR2];
    __shared__ unsigned short Bs[64 * BSTR];
    const int nwg = nrow * HEADS * 2;
    const int wgid = xcd_swizzle(blockIdx.x, nwg);
    const int tag = wgid / (nrow * HEADS);
    const int rem = wgid - tag * (nrow * HEADS);
    const int rt = rem / HEADS;
    const int head = rem - rt * HEADS;
    const float* A = tag ? x_sc : x_st;
    const unsigned short* BT = tag ? wgT_sc : wgT_st;
    const float* a_src = tag ? as_sc : as_st;
    const float* a_dst = tag ? ad_sc : ad_st;
    const int row0 = rt * 128, col0 = head * 64;
    const int tid = threadIdx.x;
    const int wv = tid >> 6, l = tid & 63;
    const int lr = l & 15, lg = l >> 4, lk = lg * 8;
    {
        int c = tid >> 2, q = tid & 3;
        const unsigned short* bp = BT + (size_t)(col0 + c) * FDIM;
        #pragma unroll
        for (int kk = q * 8; kk < FDIM; kk += 32)
            *(short8*)(Bs + c * BSTR + kk) = *(const short8*)(bp + kk);
    }
    const int arow = tid >> 1, aseg = tid & 1;
    const int gr = row0 + arow;
    f32x4 acc[2][4] = {};
    for (int ks = 0; ks < FDIM / 32; ++ks) {
        int k0 = ks * 32;
        short8 av1 = {0,0,0,0,0,0,0,0}, av2 = {0,0,0,0,0,0,0,0};
        if (gr < M) {
            const float* p = A + (size_t)gr * FDIM + k0 + aseg * 16;
            float4 x0 = *(const float4*)p;
            float4 x1 = *(const float4*)(p + 4);
            float4 x2 = *(const float4*)(p + 8);
            float4 x3 = *(const float4*)(p + 12);
            av1[0] = (short)f2bf(x0.x); av1[1] = (short)f2bf(x0.y);
            av1[2] = (short)f2bf(x0.z); av1[3] = (short)f2bf(x0.w);
            av1[4] = (short)f2bf(x1.x); av1[5] = (short)f2bf(x1.y);
            av1[6] = (short)f2bf(x1.z); av1[7] = (short)f2bf(x1.w);
            av2[0] = (short)f2bf(x2.x); av2[1] = (short)f2bf(x2.y);
            av2[2] = (short)f2bf(x2.z); av2[3] = (short)f2bf(x2.w);
            av2[4] = (short)f2bf(x3.x); av2[5] = (short)f2bf(x3.y);
            av2[6] = (short)f2bf(x3.z); av2[7] = (short)f2bf(x3.w);
        }
        *(short8*)(As + arow * ASTR2 + aseg * 16) = av1;
        *(short8*)(As + arow * ASTR2 + aseg * 16 + 8) = av2;
        __syncthreads();
        #pragma unroll
        for (int m = 0; m < 2; ++m) {
            short8 af = *(const short8*)(As + (wv * 32 + m * 16 + lr) * ASTR2 + lk);
            #pragma unroll
            for (int nb = 0; nb < 4; ++nb) {
                short8 bfm = *(const short8*)(Bs + (nb * 16 + lr) * BSTR + k0 + lk);
                acc[m][nb] = __builtin_amdgcn_mfma_f32_16x16x32_bf16(af, bfm, acc[m][nb], 0, 0, 0);
            }
        }
        __syncthreads();
    }
    const size_t tagbase = (size_t)tag * M;
    #pragma unroll
    for (int m = 0; m < 2; ++m)
        #pragma unroll
        for (int nb = 0; nb < 4; ++nb)
            #pragma unroll
            for (int r = 0; r < 4; ++r) {
                int grow = row0 + wv * 32 + m * 16 + lg * 4 + r;
                if (grow < M)
                    h_bf[(tagbase + grow) * HC + col0 + nb * 16 + lr] = f2bf(acc[m][nb][r]);
            }
    float avs[4], avd[4];
    #pragma unroll
    for (int nb = 0; nb < 4; ++nb) {
        avs[nb] = a_src[col0 + nb * 16 + lr];
        avd[nb] = a_dst[col0 + nb * 16 + lr];
    }
    #pragma unroll
    for (int m = 0; m < 2; ++m)
        #pragma unroll
        for (int r = 0; r < 4; ++r) {
            float ds = acc[m][0][r] * avs[0] + acc[m][1][r] * avs[1]
                     + acc[m][2][r] * avs[2] + acc[m][3][r] * avs[3];
            float dd = acc[m][0][r] * avd[0] + acc[m][1][r] * avd[1]
                     + acc[m][2][r] * avd[2] + acc[m][3][r] * avd[3];
            #pragma unroll
            for (int off = 8; off; off >>= 1) {
                ds += __shfl_down(ds, off);
                dd += __shfl_down(dd, off);
            }
            int grow = row0 + wv * 32 + m * 16 + lg * 4 + r;
            if (lr == 0 && grow < M) {
                ssrc[(tagbase + grow) * 3 + head] = ds;
                sdst[(tagbase + grow) * 3 + head] = dd;
            }
        }
}

// ---------------- prep: degree counts (y=0,1) + global score maxes (y=2) ----------------
__global__ __launch_bounds__(256) void prep(const int* __restrict__ ei_st,
                                            const int* __restrict__ ei_sc,
                                            int* __restrict__ deg,
                                            const float* __restrict__ ssrc,
                                            const float* __restrict__ sdst,
                                            float* __restrict__ gmax,
                                            int N, int E, int Etot) {
    if (blockIdx.y < 2) {
        int e = blockIdx.x * 256 + threadIdx.x;
        if (e >= Etot) return;
        const int* ei = blockIdx.y ? ei_sc : ei_st;
        int dst = (e < E) ? ei[E + e] : (e - E);
        atomicAdd(&deg[blockIdx.y * N + dst], 1);
        return;
    }
    if (blockIdx.x >= 32) return;   // contention guard (R3)
    __shared__ float red[4][12];
    float v[12];
    #pragma unroll
    for (int j = 0; j < 12; ++j) v[j] = -1e30f;
    const int stride = 32 * 256;
    for (int n = blockIdx.x * 256 + threadIdx.x; n < 2 * N; n += stride) {
        float s0 = ssrc[n * 3], s1 = ssrc[n * 3 + 1], s2 = ssrc[n * 3 + 2];
        float d0 = sdst[n * 3], d1 = sdst[n * 3 + 1], d2 = sdst[n * 3 + 2];
        if (n < N) {
            v[0] = fmaxf(v[0], s0); v[1] = fmaxf(v[1], s1); v[2] = fmaxf(v[2], s2);
            v[3] = fmaxf(v[3], d0); v[4] = fmaxf(v[4], d1); v[5] = fmaxf(v[5], d2);
        } else {
            v[6] = fmaxf(v[6], s0); v[7] = fmaxf(v[7], s1); v[8] = fmaxf(v[8], s2);
            v[9] = fmaxf(v[9], d0); v[10] = fmaxf(v[10], d1); v[11] = fmaxf(v[11], d2);
        }
    }
    #pragma unroll
    for (int j = 0; j < 12; ++j)
        #pragma unroll
        for (int off = 32; off; off >>= 1)
            v[j] = fmaxf(v[j], __shfl_down(v[j], off));
    int wave = threadIdx.x >> 6, lane = threadIdx.x & 63;
    if (lane == 0) {
        #pragma unroll
        for (int j = 0; j < 12; ++j) red[wave][j] = v[j];
    }
    __syncthreads();
    if (threadIdx.x < 12) {
        float m = fmaxf(fmaxf(red[0][threadIdx.x], red[1][threadIdx.x]),
                        fmaxf(red[2][threadIdx.x], red[3][threadIdx.x]));
        atomicMaxF(&gmax[threadIdx.x], m);
    }
}

// ---------------- scan ----------------
__global__ __launch_bounds__(SCAN_BLK) void scan1(const int* __restrict__ deg,
                                                  int* __restrict__ row_ptr,
                                                  int* __restrict__ bsums, int N2) {
    __shared__ int sm[SCAN_BLK];
    int tid = threadIdx.x;
    int base = blockIdx.x * SCAN_ELEMS + tid * 4;
    int v[4];
    #pragma unroll
    for (int j = 0; j < 4; ++j) v[j] = (base + j < N2) ? deg[base + j] : 0;
    int tsum = v[0] + v[1] + v[2] + v[3];
    sm[tid] = tsum;
    __syncthreads();
    for (int off = 1; off < SCAN_BLK; off <<= 1) {
        int y = (tid >= off) ? sm[tid - off] : 0;
        __syncthreads();
        sm[tid] += y;
        __syncthreads();
    }
    int run = sm[tid] - tsum;
    #pragma unroll
    for (int j = 0; j < 4; ++j) {
        if (base + j < N2) row_ptr[base + j] = run;
        run += v[j];
    }
    if (tid == SCAN_BLK - 1) bsums[blockIdx.x] = sm[SCAN_BLK - 1];
}

__global__ __launch_bounds__(SCAN_BLK) void scan2(int* __restrict__ bsums, int nb) {
    __shared__ int sm[SCAN_BLK];
    int tid = threadIdx.x;
    int v = (tid < nb) ? bsums[tid] : 0;
    sm[tid] = v;
    __syncthreads();
    for (int off = 1; off < SCAN_BLK; off <<= 1) {
        int y = (tid >= off) ? sm[tid - off] : 0;
        __syncthreads();
        sm[tid] += y;
        __syncthreads();
    }
    if (tid < nb) bsums[tid] = sm[tid] - v;
}

// ---------------- scatter (on-the-fly fixup, NT store) ----------------
__global__ __launch_bounds__(256) void scatter_p2(const int* __restrict__ ei_st,
                                                  const int* __restrict__ ei_sc,
                                                  const float* __restrict__ s_src_all,
                                                  const float* __restrict__ s_dst_all,
                                                  const float* __restrict__ gmax,
                                                  const int* __restrict__ row_ptr,
                                                  const int* __restrict__ bsums,
                                                  int* __restrict__ cursor,
                                                  f32x4* __restrict__ csr_data,
                                                  int N, int E, int Etot) {
    int e = blockIdx.x * blockDim.x + threadIdx.x;
    if (e >= Etot) return;
    const int tag = blockIdx.y;
    const int* ei = tag ? ei_sc : ei_st;
    const float* s_src = s_src_all + (size_t)tag * N * 3;
    const float* s_dst = s_dst_all + (size_t)tag * N * 3;
    const float* gm = gmax + tag * 6;
    int src, dst;
    if (e < E) { src = ei[e]; dst = ei[E + e]; } else { src = dst = e - E; }
    float M0 = leaky(gm[0] + gm[3]);
    float M1 = leaky(gm[1] + gm[4]);
    float M2 = leaky(gm[2] + gm[5]);
    float p0 = __expf(leaky(s_src[src * 3 + 0] + s_dst[dst * 3 + 0]) - M0);
    float p1 = __expf(leaky(s_src[src * 3 + 1] + s_dst[dst * 3 + 1]) - M1);
    float p2 = __expf(leaky(s_src[src * 3 + 2] + s_dst[dst * 3 + 2]) - M2);
    int g = tag * N + dst;
    int pos = row_ptr[g] + bsums[g >> 10] + atomicAdd(&cursor[g], 1);
    f32x4 val = {__int_as_float(tag * N + src), p0, p1, p2};
    __builtin_nontemporal_store(val, &csr_data[pos]);
}

// ---------------- fused aggregation + bias + ELU (round-5 shape, NT csr reads) ----------------
__global__ __launch_bounds__(256) void csr_agg2(const int* __restrict__ row_ptr,
                                                const int* __restrict__ bsums,
                                                const int* __restrict__ deg,
                                                const f32x4* __restrict__ csr_data,
                                                const unsigned short* __restrict__ Hall,
                                                const float* __restrict__ bias_st,
                                                const float* __restrict__ bias_sc,
                                                unsigned short* __restrict__ og, int N) {
    int gid = blockIdx.x * blockDim.x + threadIdx.x;
    int node = gid >> 6, lane = gid & 63;
    if (node >= 2 * N) return;
    const float* bias = (node >= N) ? bias_sc : bias_st;
    int start = row_ptr[node] + bsums[node >> 10];
    int cnt = deg[node];
    float acc0 = 0.f, acc1 = 0.f, acc2 = 0.f;
    float d0 = 0.f, d1 = 0.f, d2 = 0.f;
    int i = 0;
    for (; i + 3 < cnt; i += 4) {
        f32x4 v0 = __builtin_nontemporal_load(&csr_data[start + i]);
        f32x4 v1 = __builtin_nontemporal_load(&csr_data[start + i + 1]);
        f32x4 v2 = __builtin_nontemporal_load(&csr_data[start + i + 2]);
        f32x4 v3 = __builtin_nontemporal_load(&csr_data[start + i + 3]);
        const unsigned short* r0 =
            Hall + (size_t)__builtin_amdgcn_readfirstlane(__float_as_int(v0[0])) * HC + lane;
        const unsigned short* r1 =
            Hall + (size_t)__builtin_amdgcn_readfirstlane(__float_as_int(v1[0])) * HC + lane;
        const unsigned short* r2 =
            Hall + (size_t)__builtin_amdgcn_readfirstlane(__float_as_int(v2[0])) * HC + lane;
        const unsigned short* r3 =
            Hall + (size_t)__builtin_amdgcn_readfirstlane(__float_as_int(v3[0])) * HC + lane;
        float h00 = bf2f(r0[0]), h01 = bf2f(r0[64]), h02 = bf2f(r0[128]);
        float h10 = bf2f(r1[0]), h11 = bf2f(r1[64]), h12 = bf2f(r1[128]);
        float h20 = bf2f(r2[0]), h21 = bf2f(r2[64]), h22 = bf2f(r2[128]);
        float h30 = bf2f(r3[0]), h31 = bf2f(r3[64]), h32 = bf2f(r3[128]);
        acc0 = fmaf(v0[1], h00, acc0); acc1 = fmaf(v0[2], h01, acc1); acc2 = fmaf(v0[3], h02, acc2);
        acc0 = fmaf(v1[1], h10, acc0); acc1 = fmaf(v1[2], h11, acc1); acc2 = fmaf(v1[3], h12, acc2);
        acc0 = fmaf(v2[1], h20, acc0); acc1 = fmaf(v2[2], h21, acc1); acc2 = fmaf(v2[3], h22, acc2);
        acc0 = fmaf(v3[1], h30, acc0); acc1 = fmaf(v3[2], h31, acc1); acc2 = fmaf(v3[3], h32, acc2);
        d0 += (v0[1] + v1[1]) + (v2[1] + v3[1]);
        d1 += (v0[2] + v1[2]) + (v2[2] + v3[2]);
        d2 += (v0[3] + v1[3]) + (v2[3] + v3[3]);
    }
    for (; i < cnt; ++i) {
        f32x4 v0 = __builtin_nontemporal_load(&csr_data[start + i]);
        const unsigned short* r0 =
            Hall + (size_t)__builtin_amdgcn_readfirstlane(__float_as_int(v0[0])) * HC + lane;
        acc0 = fmaf(v0[1], bf2f(r0[0]),   acc0);
        acc1 = fmaf(v0[2], bf2f(r0[64]),  acc1);
        acc2 = fmaf(v0[3], bf2f(r0[128]), acc2);
        d0 += v0[1]; d1 += v0[2]; d2 += v0[3];
    }
    float o0 = acc0 / (d0 + 1e-16f) + bias[lane];
    float o1 = acc1 / (d1 + 1e-16f) + bias[64 + lane];
    float o2 = acc2 / (d2 + 1e-16f) + bias[128 + lane];
    o0 = o0 > 0.f ? o0 : expm1f(o0);
    o1 = o1 > 0.f ? o1 : expm1f(o1);
    o2 = o2 > 0.f ? o2 : expm1f(o2);
    unsigned short* orow = og + (size_t)node * HC + lane;
    orow[0] = f2bf(o0); orow[64] = f2bf(o1); orow[128] = f2bf(o2);
}

// ---------------- GEMM2 full-width (128 cols/block) + gelu/dot epilogue -> beta direct ----------------
__global__ __launch_bounds__(256) void gemm_beta(const unsigned short* __restrict__ og_bf,
                                                 const unsigned short* __restrict__ w1T_st,
                                                 const unsigned short* __restrict__ w1T_sc,
                                                 const float* __restrict__ b1_st,
                                                 const float* __restrict__ w2_st,
                                                 const float* __restrict__ b2_st,
                                                 const float* __restrict__ b1_sc,
                                                 const float* __restrict__ w2_sc,
                                                 const float* __restrict__ b2_sc,
                                                 float* __restrict__ beta_out,
                                                 int M, int nrow) {
    __shared__ unsigned short As[128 * ASTR2];
    __shared__ unsigned short Bs[128 * BSTRB];
    const int nwg = nrow * 2;
    const int wgid = xcd_swizzle(blockIdx.x, nwg);
    const int tag = wgid / nrow;
    const int rt = wgid - tag * nrow;
    const unsigned short* A = og_bf + (size_t)tag * M * HC;
    const unsigned short* BT = tag ? w1T_sc : w1T_st;
    const float* b1 = tag ? b1_sc : b1_st;
    const float* w2 = tag ? w2_sc : w2_st;
    const float b2v = (tag ? b2_sc : b2_st)[0];
    const int row0 = rt * 128;
    const int tid = threadIdx.x;
    const int wv = tid >> 6, l = tid & 63;
    const int lr = l & 15, lg = l >> 4, lk = lg * 8;
    // stage full B^T: 128 cols x 192 k
    {
        int c = tid >> 1, half = tid & 1;
        const unsigned short* bp = BT + (size_t)c * HC;
        #pragma unroll
        for (int j = 0; j < 12; ++j) {
            int kk = half * 96 + j * 8;
            *(short8*)(Bs + c * BSTRB + kk) = *(const short8*)(bp + kk);
        }
    }
    const int arow = tid >> 1, aseg = tid & 1;
    const int gr = row0 + arow;
    f32x4 acc[2][8] = {};
    for (int ks = 0; ks < HC / 32; ++ks) {
        int k0 = ks * 32;
        short8 av1 = {0,0,0,0,0,0,0,0}, av2 = {0,0,0,0,0,0,0,0};
        if (gr < M) {
            const unsigned short* p = A + (size_t)gr * HC + k0 + aseg * 16;
            av1 = *(const short8*)p;
            av2 = *(const short8*)(p + 8);
        }
        *(short8*)(As + arow * ASTR2 + aseg * 16) = av1;
        *(short8*)(As + arow * ASTR2 + aseg * 16 + 8) = av2;
        __syncthreads();
        #pragma unroll
        for (int m = 0; m < 2; ++m) {
            short8 af = *(const short8*)(As + (wv * 32 + m * 16 + lr) * ASTR2 + lk);
            #pragma unroll
            for (int nb = 0; nb < 8; ++nb) {
                short8 bfm = *(const short8*)(Bs + (nb * 16 + lr) * BSTRB + k0 + lk);
                acc[m][nb] = __builtin_amdgcn_mfma_f32_16x16x32_bf16(af, bfm, acc[m][nb], 0, 0, 0);
            }
        }
        __syncthreads();
    }
    float b1v[8], w2v[8];
    #pragma unroll
    for (int nb = 0; nb < 8; ++nb) {
        b1v[nb] = b1[nb * 16 + lr];
        w2v[nb] = w2[nb * 16 + lr];
    }
    #pragma unroll
    for (int m = 0; m < 2; ++m)
        #pragma unroll
        for (int r = 0; r < 4; ++r) {
            float p = 0.f;
            #pragma unroll
            for (int nb = 0; nb < 8; ++nb) {
                float vx = acc[m][nb][r] + b1v[nb];
                float g = 0.5f * vx * (1.f + erff(vx * 0.70710678118654752f));
                p = fmaf(g, w2v[nb], p);
            }
            #pragma unroll
            for (int off = 8; off; off >>= 1) p += __shfl_down(p, off);
            int grow = row0 + wv * 32 + m * 16 + lg * 4 + r;
            if (lr == 0 && grow < M)
                beta_out[(size_t)tag * M + grow] = (p + b2v) * 0.01f;
        }
}

// ---------------- z = x^T beta + fused final sigmoid (last-block) ----------------
__global__ __launch_bounds__(256) void xt_beta_final(const float* __restrict__ X_st,
                                                     const float* __restrict__ X_sc,
                                                     const float* __restrict__ beta_all,
                                                     float* __restrict__ z_all,
                                                     int* __restrict__ flag,
                                                     float* __restrict__ out, int N) {
    const int tag = blockIdx.y;
    const float* X = tag ? X_sc : X_st;
    const float* beta = beta_all + (size_t)tag * N;
    float* z = z_all + tag * FDIM;
    int f = threadIdx.x;  // 256
    int nPer = (N + gridDim.x - 1) / gridDim.x;
    int n0 = blockIdx.x * nPer;
    int n1 = min(n0 + nPer, N);
    float acc = 0.f;
    for (int n = n0; n < n1; ++n)
        acc = fmaf(X[(size_t)n * FDIM + f], beta[n], acc);
    atomicAdd(&z[f], acc);
    __threadfence();
    __syncthreads();
    __shared__ int isLast;
    if (f == 0) {
        int old = atomicAdd(flag, 1);
        isLast = (old == (int)(gridDim.x * gridDim.y) - 1);
    }
    __syncthreads();
    if (isLast) {
        float zst = atomicAdd(&z_all[f], 0.f);          // coherent cross-XCD read
        float zsc = atomicAdd(&z_all[FDIM + f], 0.f);
        float v = zsc + 0.5f * zst;
        out[f] = 1.f / (1.f + expf(-v));
    }
}

extern "C" void kernel_launch(void* const* d_in, const int* in_sizes, int n_in,
                              void* d_out, int out_size, void* d_ws, size_t ws_size,
                              hipStream_t stream) {
    const float* x_st = (const float*)d_in[0];
    const int*   ei_st = (const int*)d_in[1];
    const float* x_sc = (const float*)d_in[2];
    const int*   ei_sc = (const int*)d_in[3];
    const int N = in_sizes[0] / FDIM;
    const int E = in_sizes[1] / 2;
    const int Etot = E + N;
    const int N2 = 2 * N;

    const float* wg_st   = (const float*)d_in[4];
    const float* asrc_st = (const float*)d_in[5];
    const float* adst_st = (const float*)d_in[6];
    const float* bg_st   = (const float*)d_in[7];
    const float* w1_st   = (const float*)d_in[8];
    const float* b1_st   = (const float*)d_in[9];
    const float* w2_st   = (const float*)d_in[10];
    const float* b2_st   = (const float*)d_in[11];
    const float* wg_sc   = (const float*)d_in[12];
    const float* asrc_sc = (const float*)d_in[13];
    const float* adst_sc = (const float*)d_in[14];
    const float* bg_sc   = (const float*)d_in[15];
    const float* w1_sc   = (const float*)d_in[16];
    const float* b1_sc   = (const float*)d_in[17];
    const float* w2_sc   = (const float*)d_in[18];
    const float* b2_sc   = (const float*)d_in[19];

    float* out = (float*)d_out;
    float* beta_out = out + FDIM;   // [2N], fully written by gemm_beta

    char* wp = (char*)d_ws;
    auto alloc = [&](size_t bytes) { char* r = wp; wp += (bytes + 63) & ~(size_t)63; return r; };
    // zero block: degb[2N] | cursor[2N] | gmax[16] | zbuf[512] | flag[16]
    const int zero_ints = 2 * N2 + 16 + 512 + 16;
    int*   degb   = (int*)alloc((size_t)zero_ints * 4);
    int*   cursor = degb + N2;
    float* gmax   = (float*)(cursor + N2);
    float* zbuf   = gmax + 16;
    int*   flag   = (int*)(zbuf + 512);

    unsigned short* h_bf  = (unsigned short*)alloc((size_t)N2 * HC * 2);
    unsigned short* og_bf = (unsigned short*)alloc((size_t)N2 * HC * 2);
    f32x4*          csr_data = (f32x4*)alloc((size_t)2 * Etot * 16);
    float* ssrc = (float*)alloc((size_t)N2 * 3 * 4);
    float* sdst = (float*)alloc((size_t)N2 * 3 * 4);
    int* row_ptr = (int*)alloc((size_t)N2 * 4);
    int* bsums   = (int*)alloc(SCAN_BLK * 4);
    unsigned short* wgT_st = (unsigned short*)alloc((size_t)HC * FDIM * 2);
    unsigned short* wgT_sc = (unsigned short*)alloc((size_t)HC * FDIM * 2);
    unsigned short* w1T_st = (unsigned short*)alloc((size_t)HIDDIM * HC * 2);
    unsigned short* w1T_sc = (unsigned short*)alloc((size_t)HIDDIM * HC * 2);

    const int nb_scan = (N2 + SCAN_ELEMS - 1) / SCAN_ELEMS;
    const int nrow_t = (N + 127) / 128;

    // 1. setup: weight transposes + zeroing
    setup<<<dim3(96, 5), 256, 0, stream>>>(wg_st, wg_sc, w1_st, w1_sc,
                                           wgT_st, wgT_sc, w1T_st, w1T_sc,
                                           degb, zero_ints);

    // 2. h = bf16(x @ W) + attention scores
    gemm_attn<<<nrow_t * HEADS * 2, 256, 0, stream>>>(
        x_st, x_sc, wgT_st, wgT_sc, asrc_st, adst_st, asrc_sc, adst_sc,
        h_bf, ssrc, sdst, N, nrow_t);

    // 3. deg counts + gmax
    prep<<<dim3((Etot + 255) / 256, 3), 256, 0, stream>>>(ei_st, ei_sc, degb,
                                                          ssrc, sdst, gmax, N, E, Etot);

    // 4-5. scan
    scan1<<<nb_scan, SCAN_BLK, 0, stream>>>(degb, row_ptr, bsums, N2);
    scan2<<<1, SCAN_BLK, 0, stream>>>(bsums, nb_scan);

    // 6. scatter edges with softmax numerators
    scatter_p2<<<dim3((Etot + 255) / 256, 2), 256, 0, stream>>>(
        ei_st, ei_sc, ssrc, sdst, gmax, row_ptr, bsums, cursor, csr_data, N, E, Etot);

    // 7. fused aggregate + bias + ELU
    csr_agg2<<<(N2 + 3) / 4, 256, 0, stream>>>(row_ptr, bsums, degb, csr_data, h_bf,
                                               bg_st, bg_sc, og_bf, N);

    // 8. GEMM2 full-width + gelu/dot -> beta (direct store)
    gemm_beta<<<nrow_t * 2, 256, 0, stream>>>(og_bf, w1T_st, w1T_sc,
                                              b1_st, w2_st, b2_st,
                                              b1_sc, w2_sc, b2_sc, beta_out, N, nrow_t);

    // 9. z = x^T beta + final sigmoid (fused)
    xt_beta_final<<<dim3(512, 2), 256, 0, stream>>>(x_st, x_sc, beta_out, zbuf,
                                                    flag, out, N);
}

// Round 11
// 435.713 us; speedup vs baseline: 1.0531x; 1.0531x over previous
//
#include <hip/hip_runtime.h>
#include <math.h>

#define HEADS 3
#define CDIM 64
#define FDIM 256
#define HC 192      // HEADS*CDIM
#define HIDDIM 128
#define NEG 0.2f

#define SCAN_BLK 256
#define SCAN_ELEMS 1024  // 4 per thread; consumers use >>10

#define ASTR2 40   // LDS stride for A tiles (32 data + 8 pad shorts)
#define BSTR 264   // LDS stride for B^T tiles in gemm_attn (256 K + 8 pad)
#define BSTRB 200  // LDS stride for B^T tiles in gemm_beta (192 K + 8 pad)

typedef __attribute__((ext_vector_type(8))) short short8;
typedef __attribute__((ext_vector_type(4))) float f32x4;

__device__ __forceinline__ void atomicMaxF(float* addr, float val) {
    if (val >= 0.f) atomicMax((int*)addr, __float_as_int(val));
    else            atomicMin((unsigned int*)addr, __float_as_uint(val));
}

__device__ __forceinline__ unsigned short f2bf(float f) {
    unsigned int u = __float_as_uint(f);
    u = (u + 0x7FFFu + ((u >> 16) & 1u)) >> 16;   // RNE
    return (unsigned short)u;
}
__device__ __forceinline__ float bf2f(unsigned short u) {
    return __uint_as_float((unsigned int)u << 16);
}
__device__ __forceinline__ float leaky(float s) { return s >= 0.f ? s : NEG * s; }

// bijective chunked XCD swizzle (m204)
__device__ __forceinline__ int xcd_swizzle(int orig, int nwg) {
    int q = nwg >> 3, r = nwg & 7;
    int xcd = orig & 7, idx = orig >> 3;
    return (xcd < r ? xcd * (q + 1) : r * (q + 1) + (xcd - r) * q) + idx;
}

// ---------------- setup: weight transposes (y=0..3) + workspace zeroing (y=4) ----------------
__global__ __launch_bounds__(256) void setup(const float* __restrict__ wg_st,
                                             const float* __restrict__ wg_sc,
                                             const float* __restrict__ w1_st,
                                             const float* __restrict__ w1_sc,
                                             unsigned short* __restrict__ o0,
                                             unsigned short* __restrict__ o1,
                                             unsigned short* __restrict__ o2,
                                             unsigned short* __restrict__ o3,
                                             int* __restrict__ zero_base, int zero_ints) {
    int which = blockIdx.y;
    if (which == 4) {
        for (int i = blockIdx.x * 256 + threadIdx.x; i < zero_ints; i += gridDim.x * 256)
            zero_base[i] = 0;
        return;
    }
    const float* src = which == 0 ? wg_st : which == 1 ? wg_sc : which == 2 ? w1_st : w1_sc;
    unsigned short* dst = which == 0 ? o0 : which == 1 ? o1 : which == 2 ? o2 : o3;
    int K  = which < 2 ? FDIM : HC;
    int Nn = which < 2 ? HC : HIDDIM;
    int total = K * Nn;
    for (int idx = blockIdx.x * 256 + threadIdx.x; idx < total; idx += gridDim.x * 256) {
        int n = idx / K, k = idx - n * K;
        dst[idx] = f2bf(src[(size_t)k * Nn + n]);
    }
}

// ---------------- GEMM1 + attention-score epilogue (flattened, XCD-swizzled) ----------------
__global__ __launch_bounds__(256) void gemm_attn(const float* __restrict__ x_st,
                                                 const float* __restrict__ x_sc,
                                                 const unsigned short* __restrict__ wgT_st,
                                                 const unsigned short* __restrict__ wgT_sc,
                                                 const float* __restrict__ as_st,
                                                 const float* __restrict__ ad_st,
                                                 const float* __restrict__ as_sc,
                                                 const float* __restrict__ ad_sc,
                                                 unsigned short* __restrict__ h_bf,
                                                 float* __restrict__ ssrc,
                                                 float* __restrict__ sdst,
                                                 int M, int nrow) {
    __shared__ unsigned short As[128 * ASTR2];
    __shared__ unsigned short Bs[64 * BSTR];
    const int nwg = nrow * HEADS * 2;
    const int wgid = xcd_swizzle(blockIdx.x, nwg);
    const int tag = wgid / (nrow * HEADS);
    const int rem = wgid - tag * (nrow * HEADS);
    const int rt = rem / HEADS;
    const int head = rem - rt * HEADS;
    const float* A = tag ? x_sc : x_st;
    const unsigned short* BT = tag ? wgT_sc : wgT_st;
    const float* a_src = tag ? as_sc : as_st;
    const float* a_dst = tag ? ad_sc : ad_st;
    const int row0 = rt * 128, col0 = head * 64;
    const int tid = threadIdx.x;
    const int wv = tid >> 6, l = tid & 63;
    const int lr = l & 15, lg = l >> 4, lk = lg * 8;
    {
        int c = tid >> 2, q = tid & 3;
        const unsigned short* bp = BT + (size_t)(col0 + c) * FDIM;
        #pragma unroll
        for (int kk = q * 8; kk < FDIM; kk += 32)
            *(short8*)(Bs + c * BSTR + kk) = *(const short8*)(bp + kk);
    }
    const int arow = tid >> 1, aseg = tid & 1;
    const int gr = row0 + arow;
    f32x4 acc[2][4] = {};
    for (int ks = 0; ks < FDIM / 32; ++ks) {
        int k0 = ks * 32;
        short8 av1 = {0,0,0,0,0,0,0,0}, av2 = {0,0,0,0,0,0,0,0};
        if (gr < M) {
            const float* p = A + (size_t)gr * FDIM + k0 + aseg * 16;
            float4 x0 = *(const float4*)p;
            float4 x1 = *(const float4*)(p + 4);
            float4 x2 = *(const float4*)(p + 8);
            float4 x3 = *(const float4*)(p + 12);
            av1[0] = (short)f2bf(x0.x); av1[1] = (short)f2bf(x0.y);
            av1[2] = (short)f2bf(x0.z); av1[3] = (short)f2bf(x0.w);
            av1[4] = (short)f2bf(x1.x); av1[5] = (short)f2bf(x1.y);
            av1[6] = (short)f2bf(x1.z); av1[7] = (short)f2bf(x1.w);
            av2[0] = (short)f2bf(x2.x); av2[1] = (short)f2bf(x2.y);
            av2[2] = (short)f2bf(x2.z); av2[3] = (short)f2bf(x2.w);
            av2[4] = (short)f2bf(x3.x); av2[5] = (short)f2bf(x3.y);
            av2[6] = (short)f2bf(x3.z); av2[7] = (short)f2bf(x3.w);
        }
        *(short8*)(As + arow * ASTR2 + aseg * 16) = av1;
        *(short8*)(As + arow * ASTR2 + aseg * 16 + 8) = av2;
        __syncthreads();
        #pragma unroll
        for (int m = 0; m < 2; ++m) {
            short8 af = *(const short8*)(As + (wv * 32 + m * 16 + lr) * ASTR2 + lk);
            #pragma unroll
            for (int nb = 0; nb < 4; ++nb) {
                short8 bfm = *(const short8*)(Bs + (nb * 16 + lr) * BSTR + k0 + lk);
                acc[m][nb] = __builtin_amdgcn_mfma_f32_16x16x32_bf16(af, bfm, acc[m][nb], 0, 0, 0);
            }
        }
        __syncthreads();
    }
    const size_t tagbase = (size_t)tag * M;
    #pragma unroll
    for (int m = 0; m < 2; ++m)
        #pragma unroll
        for (int nb = 0; nb < 4; ++nb)
            #pragma unroll
            for (int r = 0; r < 4; ++r) {
                int grow = row0 + wv * 32 + m * 16 + lg * 4 + r;
                if (grow < M)
                    h_bf[(tagbase + grow) * HC + col0 + nb * 16 + lr] = f2bf(acc[m][nb][r]);
            }
    float avs[4], avd[4];
    #pragma unroll
    for (int nb = 0; nb < 4; ++nb) {
        avs[nb] = a_src[col0 + nb * 16 + lr];
        avd[nb] = a_dst[col0 + nb * 16 + lr];
    }
    #pragma unroll
    for (int m = 0; m < 2; ++m)
        #pragma unroll
        for (int r = 0; r < 4; ++r) {
            float ds = acc[m][0][r] * avs[0] + acc[m][1][r] * avs[1]
                     + acc[m][2][r] * avs[2] + acc[m][3][r] * avs[3];
            float dd = acc[m][0][r] * avd[0] + acc[m][1][r] * avd[1]
                     + acc[m][2][r] * avd[2] + acc[m][3][r] * avd[3];
            #pragma unroll
            for (int off = 8; off; off >>= 1) {
                ds += __shfl_down(ds, off);
                dd += __shfl_down(dd, off);
            }
            int grow = row0 + wv * 32 + m * 16 + lg * 4 + r;
            if (lr == 0 && grow < M) {
                ssrc[(tagbase + grow) * 3 + head] = ds;
                sdst[(tagbase + grow) * 3 + head] = dd;
            }
        }
}

// ---------------- prep: degree counts (y=0,1) + global score maxes (y=2) ----------------
__global__ __launch_bounds__(256) void prep(const int* __restrict__ ei_st,
                                            const int* __restrict__ ei_sc,
                                            int* __restrict__ deg,
                                            const float* __restrict__ ssrc,
                                            const float* __restrict__ sdst,
                                            float* __restrict__ gmax,
                                            int N, int E, int Etot) {
    if (blockIdx.y < 2) {
        int e = blockIdx.x * 256 + threadIdx.x;
        if (e >= Etot) return;
        const int* ei = blockIdx.y ? ei_sc : ei_st;
        int dst = (e < E) ? ei[E + e] : (e - E);
        atomicAdd(&deg[blockIdx.y * N + dst], 1);
        return;
    }
    if (blockIdx.x >= 32) return;   // contention guard (R3)
    __shared__ float red[4][12];
    float v[12];
    #pragma unroll
    for (int j = 0; j < 12; ++j) v[j] = -1e30f;
    const int stride = 32 * 256;
    for (int n = blockIdx.x * 256 + threadIdx.x; n < 2 * N; n += stride) {
        float s0 = ssrc[n * 3], s1 = ssrc[n * 3 + 1], s2 = ssrc[n * 3 + 2];
        float d0 = sdst[n * 3], d1 = sdst[n * 3 + 1], d2 = sdst[n * 3 + 2];
        if (n < N) {
            v[0] = fmaxf(v[0], s0); v[1] = fmaxf(v[1], s1); v[2] = fmaxf(v[2], s2);
            v[3] = fmaxf(v[3], d0); v[4] = fmaxf(v[4], d1); v[5] = fmaxf(v[5], d2);
        } else {
            v[6] = fmaxf(v[6], s0); v[7] = fmaxf(v[7], s1); v[8] = fmaxf(v[8], s2);
            v[9] = fmaxf(v[9], d0); v[10] = fmaxf(v[10], d1); v[11] = fmaxf(v[11], d2);
        }
    }
    #pragma unroll
    for (int j = 0; j < 12; ++j)
        #pragma unroll
        for (int off = 32; off; off >>= 1)
            v[j] = fmaxf(v[j], __shfl_down(v[j], off));
    int wave = threadIdx.x >> 6, lane = threadIdx.x & 63;
    if (lane == 0) {
        #pragma unroll
        for (int j = 0; j < 12; ++j) red[wave][j] = v[j];
    }
    __syncthreads();
    if (threadIdx.x < 12) {
        float m = fmaxf(fmaxf(red[0][threadIdx.x], red[1][threadIdx.x]),
                        fmaxf(red[2][threadIdx.x], red[3][threadIdx.x]));
        atomicMaxF(&gmax[threadIdx.x], m);
    }
}

// ---------------- scan ----------------
__global__ __launch_bounds__(SCAN_BLK) void scan1(const int* __restrict__ deg,
                                                  int* __restrict__ row_ptr,
                                                  int* __restrict__ bsums, int N2) {
    __shared__ int sm[SCAN_BLK];
    int tid = threadIdx.x;
    int base = blockIdx.x * SCAN_ELEMS + tid * 4;
    int v[4];
    #pragma unroll
    for (int j = 0; j < 4; ++j) v[j] = (base + j < N2) ? deg[base + j] : 0;
    int tsum = v[0] + v[1] + v[2] + v[3];
    sm[tid] = tsum;
    __syncthreads();
    for (int off = 1; off < SCAN_BLK; off <<= 1) {
        int y = (tid >= off) ? sm[tid - off] : 0;
        __syncthreads();
        sm[tid] += y;
        __syncthreads();
    }
    int run = sm[tid] - tsum;
    #pragma unroll
    for (int j = 0; j < 4; ++j) {
        if (base + j < N2) row_ptr[base + j] = run;
        run += v[j];
    }
    if (tid == SCAN_BLK - 1) bsums[blockIdx.x] = sm[SCAN_BLK - 1];
}

__global__ __launch_bounds__(SCAN_BLK) void scan2(int* __restrict__ bsums, int nb) {
    __shared__ int sm[SCAN_BLK];
    int tid = threadIdx.x;
    int v = (tid < nb) ? bsums[tid] : 0;
    sm[tid] = v;
    __syncthreads();
    for (int off = 1; off < SCAN_BLK; off <<= 1) {
        int y = (tid >= off) ? sm[tid - off] : 0;
        __syncthreads();
        sm[tid] += y;
        __syncthreads();
    }
    if (tid < nb) bsums[tid] = sm[tid] - v;
}

// ---------------- scatter (on-the-fly fixup, plain store) ----------------
__global__ __launch_bounds__(256) void scatter_p2(const int* __restrict__ ei_st,
                                                  const int* __restrict__ ei_sc,
                                                  const float* __restrict__ s_src_all,
                                                  const float* __restrict__ s_dst_all,
                                                  const float* __restrict__ gmax,
                                                  const int* __restrict__ row_ptr,
                                                  const int* __restrict__ bsums,
                                                  int* __restrict__ cursor,
                                                  f32x4* __restrict__ csr_data,
                                                  int N, int E, int Etot) {
    int e = blockIdx.x * blockDim.x + threadIdx.x;
    if (e >= Etot) return;
    const int tag = blockIdx.y;
    const int* ei = tag ? ei_sc : ei_st;
    const float* s_src = s_src_all + (size_t)tag * N * 3;
    const float* s_dst = s_dst_all + (size_t)tag * N * 3;
    const float* gm = gmax + tag * 6;
    int src, dst;
    if (e < E) { src = ei[e]; dst = ei[E + e]; } else { src = dst = e - E; }
    float M0 = leaky(gm[0] + gm[3]);
    float M1 = leaky(gm[1] + gm[4]);
    float M2 = leaky(gm[2] + gm[5]);
    float p0 = __expf(leaky(s_src[src * 3 + 0] + s_dst[dst * 3 + 0]) - M0);
    float p1 = __expf(leaky(s_src[src * 3 + 1] + s_dst[dst * 3 + 1]) - M1);
    float p2 = __expf(leaky(s_src[src * 3 + 2] + s_dst[dst * 3 + 2]) - M2);
    int g = tag * N + dst;
    int pos = row_ptr[g] + bsums[g >> 10] + atomicAdd(&cursor[g], 1);
    f32x4 val = {__int_as_float(tag * N + src), p0, p1, p2};
    csr_data[pos] = val;
}

// ---------------- fused aggregation + bias + ELU (round-5/8 shape: plain loads, unroll-4) ----------------
__global__ __launch_bounds__(256) void csr_agg2(const int* __restrict__ row_ptr,
                                                const int* __restrict__ bsums,
                                                const int* __restrict__ deg,
                                                const f32x4* __restrict__ csr_data,
                                                const unsigned short* __restrict__ Hall,
                                                const float* __restrict__ bias_st,
                                                const float* __restrict__ bias_sc,
                                                unsigned short* __restrict__ og, int N) {
    int gid = blockIdx.x * blockDim.x + threadIdx.x;
    int node = gid >> 6, lane = gid & 63;
    if (node >= 2 * N) return;
    const float* bias = (node >= N) ? bias_sc : bias_st;
    int start = row_ptr[node] + bsums[node >> 10];
    int cnt = deg[node];
    float acc0 = 0.f, acc1 = 0.f, acc2 = 0.f;
    float d0 = 0.f, d1 = 0.f, d2 = 0.f;
    int i = 0;
    for (; i + 3 < cnt; i += 4) {
        f32x4 v0 = csr_data[start + i];
        f32x4 v1 = csr_data[start + i + 1];
        f32x4 v2 = csr_data[start + i + 2];
        f32x4 v3 = csr_data[start + i + 3];
        const unsigned short* r0 =
            Hall + (size_t)__builtin_amdgcn_readfirstlane(__float_as_int(v0[0])) * HC + lane;
        const unsigned short* r1 =
            Hall + (size_t)__builtin_amdgcn_readfirstlane(__float_as_int(v1[0])) * HC + lane;
        const unsigned short* r2 =
            Hall + (size_t)__builtin_amdgcn_readfirstlane(__float_as_int(v2[0])) * HC + lane;
        const unsigned short* r3 =
            Hall + (size_t)__builtin_amdgcn_readfirstlane(__float_as_int(v3[0])) * HC + lane;
        float h00 = bf2f(r0[0]), h01 = bf2f(r0[64]), h02 = bf2f(r0[128]);
        float h10 = bf2f(r1[0]), h11 = bf2f(r1[64]), h12 = bf2f(r1[128]);
        float h20 = bf2f(r2[0]), h21 = bf2f(r2[64]), h22 = bf2f(r2[128]);
        float h30 = bf2f(r3[0]), h31 = bf2f(r3[64]), h32 = bf2f(r3[128]);
        acc0 = fmaf(v0[1], h00, acc0); acc1 = fmaf(v0[2], h01, acc1); acc2 = fmaf(v0[3], h02, acc2);
        acc0 = fmaf(v1[1], h10, acc0); acc1 = fmaf(v1[2], h11, acc1); acc2 = fmaf(v1[3], h12, acc2);
        acc0 = fmaf(v2[1], h20, acc0); acc1 = fmaf(v2[2], h21, acc1); acc2 = fmaf(v2[3], h22, acc2);
        acc0 = fmaf(v3[1], h30, acc0); acc1 = fmaf(v3[2], h31, acc1); acc2 = fmaf(v3[3], h32, acc2);
        d0 += (v0[1] + v1[1]) + (v2[1] + v3[1]);
        d1 += (v0[2] + v1[2]) + (v2[2] + v3[2]);
        d2 += (v0[3] + v1[3]) + (v2[3] + v3[3]);
    }
    for (; i < cnt; ++i) {
        f32x4 v0 = csr_data[start + i];
        const unsigned short* r0 =
            Hall + (size_t)__builtin_amdgcn_readfirstlane(__float_as_int(v0[0])) * HC + lane;
        acc0 = fmaf(v0[1], bf2f(r0[0]),   acc0);
        acc1 = fmaf(v0[2], bf2f(r0[64]),  acc1);
        acc2 = fmaf(v0[3], bf2f(r0[128]), acc2);
        d0 += v0[1]; d1 += v0[2]; d2 += v0[3];
    }
    float o0 = acc0 / (d0 + 1e-16f) + bias[lane];
    float o1 = acc1 / (d1 + 1e-16f) + bias[64 + lane];
    float o2 = acc2 / (d2 + 1e-16f) + bias[128 + lane];
    o0 = o0 > 0.f ? o0 : expm1f(o0);
    o1 = o1 > 0.f ? o1 : expm1f(o1);
    o2 = o2 > 0.f ? o2 : expm1f(o2);
    unsigned short* orow = og + (size_t)node * HC + lane;
    orow[0] = f2bf(o0); orow[64] = f2bf(o1); orow[128] = f2bf(o2);
}

// ---------------- GEMM2 full-width (128 cols/block) + gelu/dot epilogue -> beta direct ----------------
__global__ __launch_bounds__(256) void gemm_beta(const unsigned short* __restrict__ og_bf,
                                                 const unsigned short* __restrict__ w1T_st,
                                                 const unsigned short* __restrict__ w1T_sc,
                                                 const float* __restrict__ b1_st,
                                                 const float* __restrict__ w2_st,
                                                 const float* __restrict__ b2_st,
                                                 const float* __restrict__ b1_sc,
                                                 const float* __restrict__ w2_sc,
                                                 const float* __restrict__ b2_sc,
                                                 float* __restrict__ beta_out,
                                                 int M, int nrow) {
    __shared__ unsigned short As[128 * ASTR2];
    __shared__ unsigned short Bs[128 * BSTRB];
    const int nwg = nrow * 2;
    const int wgid = xcd_swizzle(blockIdx.x, nwg);
    const int tag = wgid / nrow;
    const int rt = wgid - tag * nrow;
    const unsigned short* A = og_bf + (size_t)tag * M * HC;
    const unsigned short* BT = tag ? w1T_sc : w1T_st;
    const float* b1 = tag ? b1_sc : b1_st;
    const float* w2 = tag ? w2_sc : w2_st;
    const float b2v = (tag ? b2_sc : b2_st)[0];
    const int row0 = rt * 128;
    const int tid = threadIdx.x;
    const int wv = tid >> 6, l = tid & 63;
    const int lr = l & 15, lg = l >> 4, lk = lg * 8;
    // stage full B^T: 128 cols x 192 k
    {
        int c = tid >> 1, half = tid & 1;
        const unsigned short* bp = BT + (size_t)c * HC;
        #pragma unroll
        for (int j = 0; j < 12; ++j) {
            int kk = half * 96 + j * 8;
            *(short8*)(Bs + c * BSTRB + kk) = *(const short8*)(bp + kk);
        }
    }
    const int arow = tid >> 1, aseg = tid & 1;
    const int gr = row0 + arow;
    f32x4 acc[2][8] = {};
    for (int ks = 0; ks < HC / 32; ++ks) {
        int k0 = ks * 32;
        short8 av1 = {0,0,0,0,0,0,0,0}, av2 = {0,0,0,0,0,0,0,0};
        if (gr < M) {
            const unsigned short* p = A + (size_t)gr * HC + k0 + aseg * 16;
            av1 = *(const short8*)p;
            av2 = *(const short8*)(p + 8);
        }
        *(short8*)(As + arow * ASTR2 + aseg * 16) = av1;
        *(short8*)(As + arow * ASTR2 + aseg * 16 + 8) = av2;
        __syncthreads();
        #pragma unroll
        for (int m = 0; m < 2; ++m) {
            short8 af = *(const short8*)(As + (wv * 32 + m * 16 + lr) * ASTR2 + lk);
            #pragma unroll
            for (int nb = 0; nb < 8; ++nb) {
                short8 bfm = *(const short8*)(Bs + (nb * 16 + lr) * BSTRB + k0 + lk);
                acc[m][nb] = __builtin_amdgcn_mfma_f32_16x16x32_bf16(af, bfm, acc[m][nb], 0, 0, 0);
            }
        }
        __syncthreads();
    }
    float b1v[8], w2v[8];
    #pragma unroll
    for (int nb = 0; nb < 8; ++nb) {
        b1v[nb] = b1[nb * 16 + lr];
        w2v[nb] = w2[nb * 16 + lr];
    }
    #pragma unroll
    for (int m = 0; m < 2; ++m)
        #pragma unroll
        for (int r = 0; r < 4; ++r) {
            float p = 0.f;
            #pragma unroll
            for (int nb = 0; nb < 8; ++nb) {
                float vx = acc[m][nb][r] + b1v[nb];
                float g = 0.5f * vx * (1.f + erff(vx * 0.70710678118654752f));
                p = fmaf(g, w2v[nb], p);
            }
            #pragma unroll
            for (int off = 8; off; off >>= 1) p += __shfl_down(p, off);
            int grow = row0 + wv * 32 + m * 16 + lg * 4 + r;
            if (lr == 0 && grow < M)
                beta_out[(size_t)tag * M + grow] = (p + b2v) * 0.01f;
        }
}

// ---------------- z = x^T beta + fused final sigmoid (last-block) ----------------
__global__ __launch_bounds__(256) void xt_beta_final(const float* __restrict__ X_st,
                                                     const float* __restrict__ X_sc,
                                                     const float* __restrict__ beta_all,
                                                     float* __restrict__ z_all,
                                                     int* __restrict__ flag,
                                                     float* __restrict__ out, int N) {
    const int tag = blockIdx.y;
    const float* X = tag ? X_sc : X_st;
    const float* beta = beta_all + (size_t)tag * N;
    float* z = z_all + tag * FDIM;
    int f = threadIdx.x;  // 256
    int nPer = (N + gridDim.x - 1) / gridDim.x;
    int n0 = blockIdx.x * nPer;
    int n1 = min(n0 + nPer, N);
    float acc = 0.f;
    for (int n = n0; n < n1; ++n)
        acc = fmaf(X[(size_t)n * FDIM + f], beta[n], acc);
    atomicAdd(&z[f], acc);
    __threadfence();
    __syncthreads();
    __shared__ int isLast;
    if (f == 0) {
        int old = atomicAdd(flag, 1);
        isLast = (old == (int)(gridDim.x * gridDim.y) - 1);
    }
    __syncthreads();
    if (isLast) {
        float zst = atomicAdd(&z_all[f], 0.f);          // coherent cross-XCD read
        float zsc = atomicAdd(&z_all[FDIM + f], 0.f);
        float v = zsc + 0.5f * zst;
        out[f] = 1.f / (1.f + expf(-v));
    }
}

extern "C" void kernel_launch(void* const* d_in, const int* in_sizes, int n_in,
                              void* d_out, int out_size, void* d_ws, size_t ws_size,
                              hipStream_t stream) {
    const float* x_st = (const float*)d_in[0];
    const int*   ei_st = (const int*)d_in[1];
    const float* x_sc = (const float*)d_in[2];
    const int*   ei_sc = (const int*)d_in[3];
    const int N = in_sizes[0] / FDIM;
    const int E = in_sizes[1] / 2;
    const int Etot = E + N;
    const int N2 = 2 * N;

    const float* wg_st   = (const float*)d_in[4];
    const float* asrc_st = (const float*)d_in[5];
    const float* adst_st = (const float*)d_in[6];
    const float* bg_st   = (const float*)d_in[7];
    const float* w1_st   = (const float*)d_in[8];
    const float* b1_st   = (const float*)d_in[9];
    const float* w2_st   = (const float*)d_in[10];
    const float* b2_st   = (const float*)d_in[11];
    const float* wg_sc   = (const float*)d_in[12];
    const float* asrc_sc = (const float*)d_in[13];
    const float* adst_sc = (const float*)d_in[14];
    const float* bg_sc   = (const float*)d_in[15];
    const float* w1_sc   = (const float*)d_in[16];
    const float* b1_sc   = (const float*)d_in[17];
    const float* w2_sc   = (const float*)d_in[18];
    const float* b2_sc   = (const float*)d_in[19];

    float* out = (float*)d_out;
    float* beta_out = out + FDIM;   // [2N], fully written by gemm_beta

    char* wp = (char*)d_ws;
    auto alloc = [&](size_t bytes) { char* r = wp; wp += (bytes + 63) & ~(size_t)63; return r; };
    // zero block: degb[2N] | cursor[2N] | gmax[16] | zbuf[512] | flag[16]
    const int zero_ints = 2 * N2 + 16 + 512 + 16;
    int*   degb   = (int*)alloc((size_t)zero_ints * 4);
    int*   cursor = degb + N2;
    float* gmax   = (float*)(cursor + N2);
    float* zbuf   = gmax + 16;
    int*   flag   = (int*)(zbuf + 512);

    unsigned short* h_bf  = (unsigned short*)alloc((size_t)N2 * HC * 2);
    unsigned short* og_bf = (unsigned short*)alloc((size_t)N2 * HC * 2);
    f32x4*          csr_data = (f32x4*)alloc((size_t)2 * Etot * 16);
    float* ssrc = (float*)alloc((size_t)N2 * 3 * 4);
    float* sdst = (float*)alloc((size_t)N2 * 3 * 4);
    int* row_ptr = (int*)alloc((size_t)N2 * 4);
    int* bsums   = (int*)alloc(SCAN_BLK * 4);
    unsigned short* wgT_st = (unsigned short*)alloc((size_t)HC * FDIM * 2);
    unsigned short* wgT_sc = (unsigned short*)alloc((size_t)HC * FDIM * 2);
    unsigned short* w1T_st = (unsigned short*)alloc((size_t)HIDDIM * HC * 2);
    unsigned short* w1T_sc = (unsigned short*)alloc((size_t)HIDDIM * HC * 2);

    const int nb_scan = (N2 + SCAN_ELEMS - 1) / SCAN_ELEMS;
    const int nrow_t = (N + 127) / 128;

    // 1. setup: weight transposes + zeroing
    setup<<<dim3(96, 5), 256, 0, stream>>>(wg_st, wg_sc, w1_st, w1_sc,
                                           wgT_st, wgT_sc, w1T_st, w1T_sc,
                                           degb, zero_ints);

    // 2. h = bf16(x @ W) + attention scores
    gemm_attn<<<nrow_t * HEADS * 2, 256, 0, stream>>>(
        x_st, x_sc, wgT_st, wgT_sc, asrc_st, adst_st, asrc_sc, adst_sc,
        h_bf, ssrc, sdst, N, nrow_t);

    // 3. deg counts + gmax
    prep<<<dim3((Etot + 255) / 256, 3), 256, 0, stream>>>(ei_st, ei_sc, degb,
                                                          ssrc, sdst, gmax, N, E, Etot);

    // 4-5. scan
    scan1<<<nb_scan, SCAN_BLK, 0, stream>>>(degb, row_ptr, bsums, N2);
    scan2<<<1, SCAN_BLK, 0, stream>>>(bsums, nb_scan);

    // 6. scatter edges with softmax numerators
    scatter_p2<<<dim3((Etot + 255) / 256, 2), 256, 0, stream>>>(
        ei_st, ei_sc, ssrc, sdst, gmax, row_ptr, bsums, cursor, csr_data, N, E, Etot);

    // 7. fused aggregate + bias + ELU
    csr_agg2<<<(N2 + 3) / 4, 256, 0, stream>>>(row_ptr, bsums, degb, csr_data, h_bf,
                                               bg_st, bg_sc, og_bf, N);

    // 8. GEMM2 full-width + gelu/dot -> beta (direct store)
    gemm_beta<<<nrow_t * 2, 256, 0, stream>>>(og_bf, w1T_st, w1T_sc,
                                              b1_st, w2_st, b2_st,
                                              b1_sc, w2_sc, b2_sc, beta_out, N, nrow_t);

    // 9. z = x^T beta + final sigmoid (fused)
    xt_beta_final<<<dim3(512, 2), 256, 0, stream>>>(x_st, x_sc, beta_out, zbuf,
                                                    flag, out, N);
}

// Round 12
// 385.070 us; speedup vs baseline: 1.1916x; 1.1315x over previous
//
#include <hip/hip_runtime.h>
#include <math.h>

#define HEADS 3
#define CDIM 64
#define FDIM 256
#define HC 192      // HEADS*CDIM
#define HIDDIM 128
#define NEG 0.2f

#define SCAN_BLK 256
#define SCAN_ELEMS 1024  // 4 per thread; consumers use >>10

#define ASTR2 40   // LDS stride for A tiles (32 data + 8 pad shorts)
#define BSTR 264   // LDS stride for B^T tiles in gemm_attn (256 K + 8 pad)
#define BSTRB 200  // LDS stride for B^T tiles in gemm_beta (192 K + 8 pad)

typedef __attribute__((ext_vector_type(8))) short short8;
typedef __attribute__((ext_vector_type(4))) float f32x4;

__device__ __forceinline__ void atomicMaxF(float* addr, float val) {
    if (val >= 0.f) atomicMax((int*)addr, __float_as_int(val));
    else            atomicMin((unsigned int*)addr, __float_as_uint(val));
}

__device__ __forceinline__ unsigned short f2bf(float f) {
    unsigned int u = __float_as_uint(f);
    u = (u + 0x7FFFu + ((u >> 16) & 1u)) >> 16;   // RNE
    return (unsigned short)u;
}
__device__ __forceinline__ float bf2f(unsigned short u) {
    return __uint_as_float((unsigned int)u << 16);
}
__device__ __forceinline__ float leaky(float s) { return s >= 0.f ? s : NEG * s; }

// bijective chunked XCD swizzle (m204)
__device__ __forceinline__ int xcd_swizzle(int orig, int nwg) {
    int q = nwg >> 3, r = nwg & 7;
    int xcd = orig & 7, idx = orig >> 3;
    return (xcd < r ? xcd * (q + 1) : r * (q + 1) + (xcd - r) * q) + idx;
}

// ---------------- setup: weight transposes (y=0..3) + workspace zeroing (y=4) ----------------
__global__ __launch_bounds__(256) void setup(const float* __restrict__ wg_st,
                                             const float* __restrict__ wg_sc,
                                             const float* __restrict__ w1_st,
                                             const float* __restrict__ w1_sc,
                                             unsigned short* __restrict__ o0,
                                             unsigned short* __restrict__ o1,
                                             unsigned short* __restrict__ o2,
                                             unsigned short* __restrict__ o3,
                                             int* __restrict__ zero_base, int zero_ints) {
    int which = blockIdx.y;
    if (which == 4) {
        for (int i = blockIdx.x * 256 + threadIdx.x; i < zero_ints; i += gridDim.x * 256)
            zero_base[i] = 0;
        return;
    }
    const float* src = which == 0 ? wg_st : which == 1 ? wg_sc : which == 2 ? w1_st : w1_sc;
    unsigned short* dst = which == 0 ? o0 : which == 1 ? o1 : which == 2 ? o2 : o3;
    int K  = which < 2 ? FDIM : HC;
    int Nn = which < 2 ? HC : HIDDIM;
    int total = K * Nn;
    for (int idx = blockIdx.x * 256 + threadIdx.x; idx < total; idx += gridDim.x * 256) {
        int n = idx / K, k = idx - n * K;
        dst[idx] = f2bf(src[(size_t)k * Nn + n]);
    }
}

// ---------------- GEMM1 + attention-score epilogue (flattened, XCD-swizzled) ----------------
__global__ __launch_bounds__(256) void gemm_attn(const float* __restrict__ x_st,
                                                 const float* __restrict__ x_sc,
                                                 const unsigned short* __restrict__ wgT_st,
                                                 const unsigned short* __restrict__ wgT_sc,
                                                 const float* __restrict__ as_st,
                                                 const float* __restrict__ ad_st,
                                                 const float* __restrict__ as_sc,
                                                 const float* __restrict__ ad_sc,
                                                 unsigned short* __restrict__ h_bf,
                                                 float* __restrict__ ssrc,
                                                 float* __restrict__ sdst,
                                                 int M, int nrow) {
    __shared__ unsigned short As[128 * ASTR2];
    __shared__ unsigned short Bs[64 * BSTR];
    const int nwg = nrow * HEADS * 2;
    const int wgid = xcd_swizzle(blockIdx.x, nwg);
    const int tag = wgid / (nrow * HEADS);
    const int rem = wgid - tag * (nrow * HEADS);
    const int rt = rem / HEADS;
    const int head = rem - rt * HEADS;
    const float* A = tag ? x_sc : x_st;
    const unsigned short* BT = tag ? wgT_sc : wgT_st;
    const float* a_src = tag ? as_sc : as_st;
    const float* a_dst = tag ? ad_sc : ad_st;
    const int row0 = rt * 128, col0 = head * 64;
    const int tid = threadIdx.x;
    const int wv = tid >> 6, l = tid & 63;
    const int lr = l & 15, lg = l >> 4, lk = lg * 8;
    {
        int c = tid >> 2, q = tid & 3;
        const unsigned short* bp = BT + (size_t)(col0 + c) * FDIM;
        #pragma unroll
        for (int kk = q * 8; kk < FDIM; kk += 32)
            *(short8*)(Bs + c * BSTR + kk) = *(const short8*)(bp + kk);
    }
    const int arow = tid >> 1, aseg = tid & 1;
    const int gr = row0 + arow;
    f32x4 acc[2][4] = {};
    for (int ks = 0; ks < FDIM / 32; ++ks) {
        int k0 = ks * 32;
        short8 av1 = {0,0,0,0,0,0,0,0}, av2 = {0,0,0,0,0,0,0,0};
        if (gr < M) {
            const float* p = A + (size_t)gr * FDIM + k0 + aseg * 16;
            float4 x0 = *(const float4*)p;
            float4 x1 = *(const float4*)(p + 4);
            float4 x2 = *(const float4*)(p + 8);
            float4 x3 = *(const float4*)(p + 12);
            av1[0] = (short)f2bf(x0.x); av1[1] = (short)f2bf(x0.y);
            av1[2] = (short)f2bf(x0.z); av1[3] = (short)f2bf(x0.w);
            av1[4] = (short)f2bf(x1.x); av1[5] = (short)f2bf(x1.y);
            av1[6] = (short)f2bf(x1.z); av1[7] = (short)f2bf(x1.w);
            av2[0] = (short)f2bf(x2.x); av2[1] = (short)f2bf(x2.y);
            av2[2] = (short)f2bf(x2.z); av2[3] = (short)f2bf(x2.w);
            av2[4] = (short)f2bf(x3.x); av2[5] = (short)f2bf(x3.y);
            av2[6] = (short)f2bf(x3.z); av2[7] = (short)f2bf(x3.w);
        }
        *(short8*)(As + arow * ASTR2 + aseg * 16) = av1;
        *(short8*)(As + arow * ASTR2 + aseg * 16 + 8) = av2;
        __syncthreads();
        #pragma unroll
        for (int m = 0; m < 2; ++m) {
            short8 af = *(const short8*)(As + (wv * 32 + m * 16 + lr) * ASTR2 + lk);
            #pragma unroll
            for (int nb = 0; nb < 4; ++nb) {
                short8 bfm = *(const short8*)(Bs + (nb * 16 + lr) * BSTR + k0 + lk);
                acc[m][nb] = __builtin_amdgcn_mfma_f32_16x16x32_bf16(af, bfm, acc[m][nb], 0, 0, 0);
            }
        }
        __syncthreads();
    }
    const size_t tagbase = (size_t)tag * M;
    #pragma unroll
    for (int m = 0; m < 2; ++m)
        #pragma unroll
        for (int nb = 0; nb < 4; ++nb)
            #pragma unroll
            for (int r = 0; r < 4; ++r) {
                int grow = row0 + wv * 32 + m * 16 + lg * 4 + r;
                if (grow < M)
                    h_bf[(tagbase + grow) * HC + col0 + nb * 16 + lr] = f2bf(acc[m][nb][r]);
            }
    float avs[4], avd[4];
    #pragma unroll
    for (int nb = 0; nb < 4; ++nb) {
        avs[nb] = a_src[col0 + nb * 16 + lr];
        avd[nb] = a_dst[col0 + nb * 16 + lr];
    }
    #pragma unroll
    for (int m = 0; m < 2; ++m)
        #pragma unroll
        for (int r = 0; r < 4; ++r) {
            float ds = acc[m][0][r] * avs[0] + acc[m][1][r] * avs[1]
                     + acc[m][2][r] * avs[2] + acc[m][3][r] * avs[3];
            float dd = acc[m][0][r] * avd[0] + acc[m][1][r] * avd[1]
                     + acc[m][2][r] * avd[2] + acc[m][3][r] * avd[3];
            #pragma unroll
            for (int off = 8; off; off >>= 1) {
                ds += __shfl_down(ds, off);
                dd += __shfl_down(dd, off);
            }
            int grow = row0 + wv * 32 + m * 16 + lg * 4 + r;
            if (lr == 0 && grow < M) {
                ssrc[(tagbase + grow) * 3 + head] = ds;
                sdst[(tagbase + grow) * 3 + head] = dd;
            }
        }
}

// ---------------- prep: degree counts (y=0,1) + global score maxes (y=2) ----------------
__global__ __launch_bounds__(256) void prep(const int* __restrict__ ei_st,
                                            const int* __restrict__ ei_sc,
                                            int* __restrict__ deg,
                                            const float* __restrict__ ssrc,
                                            const float* __restrict__ sdst,
                                            float* __restrict__ gmax,
                                            int N, int E, int Etot) {
    if (blockIdx.y < 2) {
        int e = blockIdx.x * 256 + threadIdx.x;
        if (e >= Etot) return;
        const int* ei = blockIdx.y ? ei_sc : ei_st;
        int dst = (e < E) ? ei[E + e] : (e - E);
        atomicAdd(&deg[blockIdx.y * N + dst], 1);
        return;
    }
    if (blockIdx.x >= 32) return;   // contention guard (R3)
    __shared__ float red[4][12];
    float v[12];
    #pragma unroll
    for (int j = 0; j < 12; ++j) v[j] = -1e30f;
    const int stride = 32 * 256;
    for (int n = blockIdx.x * 256 + threadIdx.x; n < 2 * N; n += stride) {
        float s0 = ssrc[n * 3], s1 = ssrc[n * 3 + 1], s2 = ssrc[n * 3 + 2];
        float d0 = sdst[n * 3], d1 = sdst[n * 3 + 1], d2 = sdst[n * 3 + 2];
        if (n < N) {
            v[0] = fmaxf(v[0], s0); v[1] = fmaxf(v[1], s1); v[2] = fmaxf(v[2], s2);
            v[3] = fmaxf(v[3], d0); v[4] = fmaxf(v[4], d1); v[5] = fmaxf(v[5], d2);
        } else {
            v[6] = fmaxf(v[6], s0); v[7] = fmaxf(v[7], s1); v[8] = fmaxf(v[8], s2);
            v[9] = fmaxf(v[9], d0); v[10] = fmaxf(v[10], d1); v[11] = fmaxf(v[11], d2);
        }
    }
    #pragma unroll
    for (int j = 0; j < 12; ++j)
        #pragma unroll
        for (int off = 32; off; off >>= 1)
            v[j] = fmaxf(v[j], __shfl_down(v[j], off));
    int wave = threadIdx.x >> 6, lane = threadIdx.x & 63;
    if (lane == 0) {
        #pragma unroll
        for (int j = 0; j < 12; ++j) red[wave][j] = v[j];
    }
    __syncthreads();
    if (threadIdx.x < 12) {
        float m = fmaxf(fmaxf(red[0][threadIdx.x], red[1][threadIdx.x]),
                        fmaxf(red[2][threadIdx.x], red[3][threadIdx.x]));
        atomicMaxF(&gmax[threadIdx.x], m);
    }
}

// ---------------- scan ----------------
__global__ __launch_bounds__(SCAN_BLK) void scan1(const int* __restrict__ deg,
                                                  int* __restrict__ row_ptr,
                                                  int* __restrict__ bsums, int N2) {
    __shared__ int sm[SCAN_BLK];
    int tid = threadIdx.x;
    int base = blockIdx.x * SCAN_ELEMS + tid * 4;
    int v[4];
    #pragma unroll
    for (int j = 0; j < 4; ++j) v[j] = (base + j < N2) ? deg[base + j] : 0;
    int tsum = v[0] + v[1] + v[2] + v[3];
    sm[tid] = tsum;
    __syncthreads();
    for (int off = 1; off < SCAN_BLK; off <<= 1) {
        int y = (tid >= off) ? sm[tid - off] : 0;
        __syncthreads();
        sm[tid] += y;
        __syncthreads();
    }
    int run = sm[tid] - tsum;
    #pragma unroll
    for (int j = 0; j < 4; ++j) {
        if (base + j < N2) row_ptr[base + j] = run;
        run += v[j];
    }
    if (tid == SCAN_BLK - 1) bsums[blockIdx.x] = sm[SCAN_BLK - 1];
}

__global__ __launch_bounds__(SCAN_BLK) void scan2(int* __restrict__ bsums, int nb) {
    __shared__ int sm[SCAN_BLK];
    int tid = threadIdx.x;
    int v = (tid < nb) ? bsums[tid] : 0;
    sm[tid] = v;
    __syncthreads();
    for (int off = 1; off < SCAN_BLK; off <<= 1) {
        int y = (tid >= off) ? sm[tid - off] : 0;
        __syncthreads();
        sm[tid] += y;
        __syncthreads();
    }
    if (tid < nb) bsums[tid] = sm[tid] - v;
}

// ---------------- scatter (on-the-fly fixup, plain store) ----------------
__global__ __launch_bounds__(256) void scatter_p2(const int* __restrict__ ei_st,
                                                  const int* __restrict__ ei_sc,
                                                  const float* __restrict__ s_src_all,
                                                  const float* __restrict__ s_dst_all,
                                                  const float* __restrict__ gmax,
                                                  const int* __restrict__ row_ptr,
                                                  const int* __restrict__ bsums,
                                                  int* __restrict__ cursor,
                                                  f32x4* __restrict__ csr_data,
                                                  int N, int E, int Etot) {
    int e = blockIdx.x * blockDim.x + threadIdx.x;
    if (e >= Etot) return;
    const int tag = blockIdx.y;
    const int* ei = tag ? ei_sc : ei_st;
    const float* s_src = s_src_all + (size_t)tag * N * 3;
    const float* s_dst = s_dst_all + (size_t)tag * N * 3;
    const float* gm = gmax + tag * 6;
    int src, dst;
    if (e < E) { src = ei[e]; dst = ei[E + e]; } else { src = dst = e - E; }
    float M0 = leaky(gm[0] + gm[3]);
    float M1 = leaky(gm[1] + gm[4]);
    float M2 = leaky(gm[2] + gm[5]);
    float p0 = __expf(leaky(s_src[src * 3 + 0] + s_dst[dst * 3 + 0]) - M0);
    float p1 = __expf(leaky(s_src[src * 3 + 1] + s_dst[dst * 3 + 1]) - M1);
    float p2 = __expf(leaky(s_src[src * 3 + 2] + s_dst[dst * 3 + 2]) - M2);
    int g = tag * N + dst;
    int pos = row_ptr[g] + bsums[g >> 10] + atomicAdd(&cursor[g], 1);
    f32x4 val = {__int_as_float(tag * N + src), p0, p1, p2};
    csr_data[pos] = val;
}

// ---------------- fused aggregation + bias + ELU (round-5/8 shape: plain loads, unroll-4) ----------------
__global__ __launch_bounds__(256) void csr_agg2(const int* __restrict__ row_ptr,
                                                const int* __restrict__ bsums,
                                                const int* __restrict__ deg,
                                                const f32x4* __restrict__ csr_data,
                                                const unsigned short* __restrict__ Hall,
                                                const float* __restrict__ bias_st,
                                                const float* __restrict__ bias_sc,
                                                unsigned short* __restrict__ og, int N) {
    int gid = blockIdx.x * blockDim.x + threadIdx.x;
    int node = gid >> 6, lane = gid & 63;
    if (node >= 2 * N) return;
    const float* bias = (node >= N) ? bias_sc : bias_st;
    int start = row_ptr[node] + bsums[node >> 10];
    int cnt = deg[node];
    float acc0 = 0.f, acc1 = 0.f, acc2 = 0.f;
    float d0 = 0.f, d1 = 0.f, d2 = 0.f;
    int i = 0;
    for (; i + 3 < cnt; i += 4) {
        f32x4 v0 = csr_data[start + i];
        f32x4 v1 = csr_data[start + i + 1];
        f32x4 v2 = csr_data[start + i + 2];
        f32x4 v3 = csr_data[start + i + 3];
        const unsigned short* r0 =
            Hall + (size_t)__builtin_amdgcn_readfirstlane(__float_as_int(v0[0])) * HC + lane;
        const unsigned short* r1 =
            Hall + (size_t)__builtin_amdgcn_readfirstlane(__float_as_int(v1[0])) * HC + lane;
        const unsigned short* r2 =
            Hall + (size_t)__builtin_amdgcn_readfirstlane(__float_as_int(v2[0])) * HC + lane;
        const unsigned short* r3 =
            Hall + (size_t)__builtin_amdgcn_readfirstlane(__float_as_int(v3[0])) * HC + lane;
        float h00 = bf2f(r0[0]), h01 = bf2f(r0[64]), h02 = bf2f(r0[128]);
        float h10 = bf2f(r1[0]), h11 = bf2f(r1[64]), h12 = bf2f(r1[128]);
        float h20 = bf2f(r2[0]), h21 = bf2f(r2[64]), h22 = bf2f(r2[128]);
        float h30 = bf2f(r3[0]), h31 = bf2f(r3[64]), h32 = bf2f(r3[128]);
        acc0 = fmaf(v0[1], h00, acc0); acc1 = fmaf(v0[2], h01, acc1); acc2 = fmaf(v0[3], h02, acc2);
        acc0 = fmaf(v1[1], h10, acc0); acc1 = fmaf(v1[2], h11, acc1); acc2 = fmaf(v1[3], h12, acc2);
        acc0 = fmaf(v2[1], h20, acc0); acc1 = fmaf(v2[2], h21, acc1); acc2 = fmaf(v2[3], h22, acc2);
        acc0 = fmaf(v3[1], h30, acc0); acc1 = fmaf(v3[2], h31, acc1); acc2 = fmaf(v3[3], h32, acc2);
        d0 += (v0[1] + v1[1]) + (v2[1] + v3[1]);
        d1 += (v0[2] + v1[2]) + (v2[2] + v3[2]);
        d2 += (v0[3] + v1[3]) + (v2[3] + v3[3]);
    }
    for (; i < cnt; ++i) {
        f32x4 v0 = csr_data[start + i];
        const unsigned short* r0 =
            Hall + (size_t)__builtin_amdgcn_readfirstlane(__float_as_int(v0[0])) * HC + lane;
        acc0 = fmaf(v0[1], bf2f(r0[0]),   acc0);
        acc1 = fmaf(v0[2], bf2f(r0[64]),  acc1);
        acc2 = fmaf(v0[3], bf2f(r0[128]), acc2);
        d0 += v0[1]; d1 += v0[2]; d2 += v0[3];
    }
    float o0 = acc0 / (d0 + 1e-16f) + bias[lane];
    float o1 = acc1 / (d1 + 1e-16f) + bias[64 + lane];
    float o2 = acc2 / (d2 + 1e-16f) + bias[128 + lane];
    o0 = o0 > 0.f ? o0 : expm1f(o0);
    o1 = o1 > 0.f ? o1 : expm1f(o1);
    o2 = o2 > 0.f ? o2 : expm1f(o2);
    unsigned short* orow = og + (size_t)node * HC + lane;
    orow[0] = f2bf(o0); orow[64] = f2bf(o1); orow[128] = f2bf(o2);
}

// ---------------- GEMM2 full-width (128 cols/block) + gelu/dot epilogue -> beta direct ----------------
__global__ __launch_bounds__(256) void gemm_beta(const unsigned short* __restrict__ og_bf,
                                                 const unsigned short* __restrict__ w1T_st,
                                                 const unsigned short* __restrict__ w1T_sc,
                                                 const float* __restrict__ b1_st,
                                                 const float* __restrict__ w2_st,
                                                 const float* __restrict__ b2_st,
                                                 const float* __restrict__ b1_sc,
                                                 const float* __restrict__ w2_sc,
                                                 const float* __restrict__ b2_sc,
                                                 float* __restrict__ beta_out,
                                                 int M, int nrow) {
    __shared__ unsigned short As[128 * ASTR2];
    __shared__ unsigned short Bs[128 * BSTRB];
    const int nwg = nrow * 2;
    const int wgid = xcd_swizzle(blockIdx.x, nwg);
    const int tag = wgid / nrow;
    const int rt = wgid - tag * nrow;
    const unsigned short* A = og_bf + (size_t)tag * M * HC;
    const unsigned short* BT = tag ? w1T_sc : w1T_st;
    const float* b1 = tag ? b1_sc : b1_st;
    const float* w2 = tag ? w2_sc : w2_st;
    const float b2v = (tag ? b2_sc : b2_st)[0];
    const int row0 = rt * 128;
    const int tid = threadIdx.x;
    const int wv = tid >> 6, l = tid & 63;
    const int lr = l & 15, lg = l >> 4, lk = lg * 8;
    // stage full B^T: 128 cols x 192 k
    {
        int c = tid >> 1, half = tid & 1;
        const unsigned short* bp = BT + (size_t)c * HC;
        #pragma unroll
        for (int j = 0; j < 12; ++j) {
            int kk = half * 96 + j * 8;
            *(short8*)(Bs + c * BSTRB + kk) = *(const short8*)(bp + kk);
        }
    }
    const int arow = tid >> 1, aseg = tid & 1;
    const int gr = row0 + arow;
    f32x4 acc[2][8] = {};
    for (int ks = 0; ks < HC / 32; ++ks) {
        int k0 = ks * 32;
        short8 av1 = {0,0,0,0,0,0,0,0}, av2 = {0,0,0,0,0,0,0,0};
        if (gr < M) {
            const unsigned short* p = A + (size_t)gr * HC + k0 + aseg * 16;
            av1 = *(const short8*)p;
            av2 = *(const short8*)(p + 8);
        }
        *(short8*)(As + arow * ASTR2 + aseg * 16) = av1;
        *(short8*)(As + arow * ASTR2 + aseg * 16 + 8) = av2;
        __syncthreads();
        #pragma unroll
        for (int m = 0; m < 2; ++m) {
            short8 af = *(const short8*)(As + (wv * 32 + m * 16 + lr) * ASTR2 + lk);
            #pragma unroll
            for (int nb = 0; nb < 8; ++nb) {
                short8 bfm = *(const short8*)(Bs + (nb * 16 + lr) * BSTRB + k0 + lk);
                acc[m][nb] = __builtin_amdgcn_mfma_f32_16x16x32_bf16(af, bfm, acc[m][nb], 0, 0, 0);
            }
        }
        __syncthreads();
    }
    float b1v[8], w2v[8];
    #pragma unroll
    for (int nb = 0; nb < 8; ++nb) {
        b1v[nb] = b1[nb * 16 + lr];
        w2v[nb] = w2[nb * 16 + lr];
    }
    #pragma unroll
    for (int m = 0; m < 2; ++m)
        #pragma unroll
        for (int r = 0; r < 4; ++r) {
            float p = 0.f;
            #pragma unroll
            for (int nb = 0; nb < 8; ++nb) {
                float vx = acc[m][nb][r] + b1v[nb];
                float g = 0.5f * vx * (1.f + erff(vx * 0.70710678118654752f));
                p = fmaf(g, w2v[nb], p);
            }
            #pragma unroll
            for (int off = 8; off; off >>= 1) p += __shfl_down(p, off);
            int grow = row0 + wv * 32 + m * 16 + lg * 4 + r;
            if (lr == 0 && grow < M)
                beta_out[(size_t)tag * M + grow] = (p + b2v) * 0.01f;
        }
}

// ---------------- z = x^T beta ----------------
__global__ __launch_bounds__(256) void xt_beta2(const float* __restrict__ X_st,
                                                const float* __restrict__ X_sc,
                                                const float* __restrict__ beta_all,
                                                float* __restrict__ z_all, int N) {
    const int tag = blockIdx.y;
    const float* X = tag ? X_sc : X_st;
    const float* beta = beta_all + (size_t)tag * N;
    float* z = z_all + tag * FDIM;
    int f = threadIdx.x;  // 256
    int nPer = (N + gridDim.x - 1) / gridDim.x;
    int n0 = blockIdx.x * nPer;
    int n1 = min(n0 + nPer, N);
    float acc = 0.f;
    for (int n = n0; n < n1; ++n)
        acc = fmaf(X[(size_t)n * FDIM + f], beta[n], acc);
    atomicAdd(&z[f], acc);
}

__global__ void final_sigmoid(const float* __restrict__ z_all,
                              float* __restrict__ out) {
    int f = threadIdx.x;
    float v = z_all[FDIM + f] + 0.5f * z_all[f];
    out[f] = 1.f / (1.f + expf(-v));
}

extern "C" void kernel_launch(void* const* d_in, const int* in_sizes, int n_in,
                              void* d_out, int out_size, void* d_ws, size_t ws_size,
                              hipStream_t stream) {
    const float* x_st = (const float*)d_in[0];
    const int*   ei_st = (const int*)d_in[1];
    const float* x_sc = (const float*)d_in[2];
    const int*   ei_sc = (const int*)d_in[3];
    const int N = in_sizes[0] / FDIM;
    const int E = in_sizes[1] / 2;
    const int Etot = E + N;
    const int N2 = 2 * N;

    const float* wg_st   = (const float*)d_in[4];
    const float* asrc_st = (const float*)d_in[5];
    const float* adst_st = (const float*)d_in[6];
    const float* bg_st   = (const float*)d_in[7];
    const float* w1_st   = (const float*)d_in[8];
    const float* b1_st   = (const float*)d_in[9];
    const float* w2_st   = (const float*)d_in[10];
    const float* b2_st   = (const float*)d_in[11];
    const float* wg_sc   = (const float*)d_in[12];
    const float* asrc_sc = (const float*)d_in[13];
    const float* adst_sc = (const float*)d_in[14];
    const float* bg_sc   = (const float*)d_in[15];
    const float* w1_sc   = (const float*)d_in[16];
    const float* b1_sc   = (const float*)d_in[17];
    const float* w2_sc   = (const float*)d_in[18];
    const float* b2_sc   = (const float*)d_in[19];

    float* out = (float*)d_out;
    float* beta_out = out + FDIM;   // [2N], fully written by gemm_beta

    char* wp = (char*)d_ws;
    auto alloc = [&](size_t bytes) { char* r = wp; wp += (bytes + 63) & ~(size_t)63; return r; };
    // zero block: degb[2N] | cursor[2N] | gmax[16] | zbuf[512]
    const int zero_ints = 2 * N2 + 16 + 512;
    int*   degb   = (int*)alloc((size_t)zero_ints * 4);
    int*   cursor = degb + N2;
    float* gmax   = (float*)(cursor + N2);
    float* zbuf   = gmax + 16;

    unsigned short* h_bf  = (unsigned short*)alloc((size_t)N2 * HC * 2);
    unsigned short* og_bf = (unsigned short*)alloc((size_t)N2 * HC * 2);
    f32x4*          csr_data = (f32x4*)alloc((size_t)2 * Etot * 16);
    float* ssrc = (float*)alloc((size_t)N2 * 3 * 4);
    float* sdst = (float*)alloc((size_t)N2 * 3 * 4);
    int* row_ptr = (int*)alloc((size_t)N2 * 4);
    int* bsums   = (int*)alloc(SCAN_BLK * 4);
    unsigned short* wgT_st = (unsigned short*)alloc((size_t)HC * FDIM * 2);
    unsigned short* wgT_sc = (unsigned short*)alloc((size_t)HC * FDIM * 2);
    unsigned short* w1T_st = (unsigned short*)alloc((size_t)HIDDIM * HC * 2);
    unsigned short* w1T_sc = (unsigned short*)alloc((size_t)HIDDIM * HC * 2);

    const int nb_scan = (N2 + SCAN_ELEMS - 1) / SCAN_ELEMS;
    const int nrow_t = (N + 127) / 128;

    // 1. setup: weight transposes + zeroing
    setup<<<dim3(96, 5), 256, 0, stream>>>(wg_st, wg_sc, w1_st, w1_sc,
                                           wgT_st, wgT_sc, w1T_st, w1T_sc,
                                           degb, zero_ints);

    // 2. h = bf16(x @ W) + attention scores
    gemm_attn<<<nrow_t * HEADS * 2, 256, 0, stream>>>(
        x_st, x_sc, wgT_st, wgT_sc, asrc_st, adst_st, asrc_sc, adst_sc,
        h_bf, ssrc, sdst, N, nrow_t);

    // 3. deg counts + gmax
    prep<<<dim3((Etot + 255) / 256, 3), 256, 0, stream>>>(ei_st, ei_sc, degb,
                                                          ssrc, sdst, gmax, N, E, Etot);

    // 4-5. scan
    scan1<<<nb_scan, SCAN_BLK, 0, stream>>>(degb, row_ptr, bsums, N2);
    scan2<<<1, SCAN_BLK, 0, stream>>>(bsums, nb_scan);

    // 6. scatter edges with softmax numerators
    scatter_p2<<<dim3((Etot + 255) / 256, 2), 256, 0, stream>>>(
        ei_st, ei_sc, ssrc, sdst, gmax, row_ptr, bsums, cursor, csr_data, N, E, Etot);

    // 7. fused aggregate + bias + ELU
    csr_agg2<<<(N2 + 3) / 4, 256, 0, stream>>>(row_ptr, bsums, degb, csr_data, h_bf,
                                               bg_st, bg_sc, og_bf, N);

    // 8. GEMM2 full-width + gelu/dot -> beta (direct store)
    gemm_beta<<<nrow_t * 2, 256, 0, stream>>>(og_bf, w1T_st, w1T_sc,
                                              b1_st, w2_st, b2_st,
                                              b1_sc, w2_sc, b2_sc, beta_out, N, nrow_t);

    // 9. z = x^T beta
    xt_beta2<<<dim3(512, 2), 256, 0, stream>>>(x_st, x_sc, beta_out, zbuf, N);

    // 10. final sigmoid
    final_sigmoid<<<1, FDIM, 0, stream>>>(zbuf, out);
}